// Round 2
// baseline (850.629 us; speedup 1.0000x reference)
//
#include <hip/hip_runtime.h>
#include <hip/hip_bf16.h>

typedef _Float16 f16x8 __attribute__((ext_vector_type(8)));
typedef float f32x4 __attribute__((ext_vector_type(4)));

#define NN 10000            // num_nodes (fixed by setup_inputs)
#define XROW 576            // 9*64 fp32 elements per edge row
#define BT_P0 73728         // 384*192
#define BT_P1 131072        // 512*256
#define BT_P2 32768         // 256*128
#define BT_TOT 237568

// -------- weight packing: W fp32 [19][64][128] -> fp16 blockdiag BT[n][k], signs folded ------
__global__ void prep_bt(const float* __restrict__ Wq, const float* __restrict__ Wk,
                        _Float16* __restrict__ bt) {
    int tid = blockIdx.x * 256 + threadIdx.x;
    if (tid >= 2 * BT_TOT) return;
    int t = tid / BT_TOT;            // 0 = q, 1 = k
    int r = tid - t * BT_TOT;
    const float* W = t ? Wk : Wq;
    int p, base, KP;
    if (r < BT_P0)              { p = 0; base = 0;             KP = 192; }
    else if (r < BT_P0 + BT_P1) { p = 1; base = BT_P0;         KP = 256; }
    else                        { p = 2; base = BT_P0 + BT_P1; KP = 128; }
    int local = r - base;
    int n = local / KP, k = local - n * KP;
    int ib = k >> 6, c = k & 63;     // input 64-block, channel
    int ob = n >> 7, d = n & 127;    // output 128-block, channel
    int w, neg = 0;
    if (p == 0) {
        w = ib * 3 + ob;             // Wm[i,o] i-major
    } else {
        int i, o, xn, yn, nb;
        if (p == 1) { i = ib & 1; xn = ib >> 1; o = ob & 1; yn = ob >> 1; nb = 9 + i * 4 + o * 2; }
        else        { xn = ib;   o = 0; yn = ob; nb = 17; }
        int which = xn ^ yn;         // 0 -> Wr, 1 -> Wi
        w = nb + which;
        neg = xn & (yn ^ 1);         // -Wi feeds the y_p path
    }
    float v = W[w * 8192 + c * 128 + d];
    if (neg) v = -v;
    bt[tid] = (_Float16)v;           // dest layout == tid by construction
}

// -------- main: per-wave 16-edge subtile, 3 SO(2) phases, fused q.k reduction ----------------
__launch_bounds__(256)
__global__ void so2_attn_main(const float* __restrict__ xq, const float* __restrict__ xk,
                              const ushort* __restrict__ bt, const int* __restrict__ index,
                              float* __restrict__ pre, unsigned int* __restrict__ segmax, int E)
{
    __shared__ __align__(16) ushort lbq[16 * 264];
    __shared__ __align__(16) ushort lbk[16 * 264];

    const int tid  = threadIdx.x;
    const int wave = tid >> 6, lane = tid & 63;
    const int rsub = lane & 15, quad = lane >> 4;
    const int e0w  = blockIdx.x * 64 + wave * 16;

    float pacc[8][4];
#pragma unroll
    for (int h = 0; h < 8; ++h)
#pragma unroll
        for (int r = 0; r < 4; ++r) pacc[h][r] = 0.f;

    int eA = e0w + rsub; if (eA >= E) eA = E - 1;     // clamp A-row loads; writes guarded later
    const float* xqrow = xq + (size_t)eA * XROW;
    const float* xkrow = xk + (size_t)eA * XROW;

    constexpr int KP_[3]      = {192, 256, 128};
    constexpr int NI_[3]      = {3, 4, 2};
    constexpr int NOB_[3]     = {3, 4, 2};
    constexpr int BTO_[3]     = {0, BT_P0, BT_P0 + BT_P1};
    constexpr int IORD[3][4]  = {{0, 2, 6, 0}, {3, 7, 1, 5}, {8, 4, 0, 0}};

#pragma unroll
    for (int p = 0; p < 3; ++p) {
        const int KP = KP_[p], NI = NI_[p], NOB = NOB_[p];
        const int KPAD = KP + 8;
        const int KC = KP / 32;          // MFMAs per acc: 6 / 8 / 4
        // ---- A fragments: fp32 global loads, converted to fp16 in-register ----
        f16x8 aq[8], ak[8];
#pragma unroll
        for (int i = 0; i < NI; ++i)
#pragma unroll
            for (int kh = 0; kh < 2; ++kh) {
                int off = IORD[p][i] * 64 + kh * 32 + quad * 8;
                f32x4 q0 = *(const f32x4*)(xqrow + off);
                f32x4 q1 = *(const f32x4*)(xqrow + off + 4);
                f32x4 k0 = *(const f32x4*)(xkrow + off);
                f32x4 k1 = *(const f32x4*)(xkrow + off + 4);
                f16x8 fq, fk;
#pragma unroll
                for (int j = 0; j < 4; ++j) {
                    fq[j] = (_Float16)q0[j]; fq[4 + j] = (_Float16)q1[j];
                    fk[j] = (_Float16)k0[j]; fk[4 + j] = (_Float16)k1[j];
                }
                aq[i * 2 + kh] = fq;
                ak[i * 2 + kh] = fk;
            }
        const ushort* btq = bt + BTO_[p];
        const ushort* btk = btq + BT_TOT;
        const int UPR = KP / 8;          // 16B units per BT row
        const int UT  = 16 * UPR;        // units per tensor per 16-col chunk
        const int JN  = (2 * UT) / 256;  // units per thread (3/4/2, exact)

        for (int ob = 0; ob < NOB; ++ob) {
#pragma unroll
            for (int h = 0; h < 8; ++h) {
                const int nt = ob * 8 + h;
                // ---- stage B chunk (q & k), 16 cols x KP fp16, padded rows ----
#pragma unroll
                for (int j = 0; j < JN; ++j) {
                    int u   = tid + j * 256;
                    int tt  = u / UT;
                    int rem = u - tt * UT;
                    int row = rem / UPR;
                    int cu  = rem - row * UPR;
                    const ushort* src = (tt ? btk : btq) + (size_t)(nt * 16 + row) * KP + cu * 8;
                    ushort* dst = (tt ? lbk : lbq) + row * KPAD + cu * 8;
                    *(uint4*)dst = *(const uint4*)src;
                }
                __syncthreads();
                f32x4 qa = {0.f, 0.f, 0.f, 0.f}, ka = {0.f, 0.f, 0.f, 0.f};
#pragma unroll
                for (int kc = 0; kc < KC; ++kc) {
                    const int lo = rsub * KPAD + kc * 32 + quad * 8;
                    f16x8 bq = *(const f16x8*)(lbq + lo);
                    f16x8 bk = *(const f16x8*)(lbk + lo);
                    qa = __builtin_amdgcn_mfma_f32_16x16x32_f16(aq[kc], bq, qa, 0, 0, 0);
                    ka = __builtin_amdgcn_mfma_f32_16x16x32_f16(ak[kc], bk, ka, 0, 0, 0);
                }
#pragma unroll
                for (int r = 0; r < 4; ++r) pacc[h][r] += qa[r] * ka[r];
                __syncthreads();
            }
        }
    }

    // ---- epilogue: reduce 16 channels per head across lanes, write pre + seg-max atomic ----
#pragma unroll
    for (int h = 0; h < 8; ++h) {
        float v[4];
#pragma unroll
        for (int r = 0; r < 4; ++r) v[r] = pacc[h][r] * 0.25f;   // * K_C^-0.5
#pragma unroll
        for (int off = 8; off >= 1; off >>= 1)
#pragma unroll
            for (int r = 0; r < 4; ++r) v[r] += __shfl_xor(v[r], off, 64);
        if (rsub == h) {
#pragma unroll
            for (int r = 0; r < 4; ++r) {
                int e = e0w + quad * 4 + r;
                if (e < E) {
                    pre[(size_t)e * 8 + h] = v[r];
                    unsigned u = __float_as_uint(v[r]);
                    u = (u & 0x80000000u) ? ~u : (u | 0x80000000u);   // order-preserving map
                    atomicMax(&segmax[(size_t)index[e] * 8 + h], u);
                }
            }
        }
    }
}

// ---------------- softmax passes ----------------
__global__ void exp_seg(const int* __restrict__ index, float* __restrict__ pre,
                        const unsigned* __restrict__ segmax, float* __restrict__ segsum, int E) {
    int idx = blockIdx.x * 256 + threadIdx.x;
    if (idx >= E * 8) return;
    int e = idx >> 3, h = idx & 7;
    unsigned um = segmax[(size_t)index[e] * 8 + h];
    unsigned ub = (um & 0x80000000u) ? (um & 0x7FFFFFFFu) : ~um;
    float m = __uint_as_float(ub);
    float ex = __expf(pre[idx] - m);
    pre[idx] = ex;
    atomicAdd(&segsum[(size_t)index[e] * 8 + h], ex);
}

__global__ void finalize(const int* __restrict__ index, const float* __restrict__ pre,
                         const float* __restrict__ segsum, float* __restrict__ out, int E) {
    int idx = blockIdx.x * 256 + threadIdx.x;
    if (idx >= E * 8) return;
    int e = idx >> 3, h = idx & 7;
    float s = segsum[(size_t)index[e] * 8 + h] + 1e-16f;
    out[idx] = pre[idx] / s;
}

extern "C" void kernel_launch(void* const* d_in, const int* in_sizes, int n_in,
                              void* d_out, int out_size, void* d_ws, size_t ws_size,
                              hipStream_t stream) {
    const float* xq = (const float*)d_in[0];
    const float* xk = (const float*)d_in[1];
    const float* Wq = (const float*)d_in[2];
    const float* Wk = (const float*)d_in[3];
    const int* index = (const int*)d_in[4];
    const int E = in_sizes[0] / XROW;        // 100000

    char* ws = (char*)d_ws;
    _Float16* bt     = (_Float16*)ws;                                 // 2*BT_TOT fp16 = 950272 B
    float*    pre    = (float*)(ws + (size_t)2 * BT_TOT * 2);         // E*8 f32
    unsigned* segmax = (unsigned*)((char*)pre + (size_t)E * 8 * 4);   // NN*8 u32
    float*    segsum = (float*)((char*)segmax + (size_t)NN * 8 * 4);  // NN*8 f32

    hipMemsetAsync(segmax, 0, (size_t)NN * 8 * 4 * 2, stream);        // segmax enc-bottom + segsum 0

    prep_bt<<<(2 * BT_TOT + 255) / 256, 256, 0, stream>>>(Wq, Wk, bt);
    so2_attn_main<<<(E + 63) / 64, 256, 0, stream>>>(xq, xk, (const ushort*)bt, index,
                                                     pre, segmax, E);
    int n2 = (E * 8 + 255) / 256;
    exp_seg<<<n2, 256, 0, stream>>>(index, pre, segmax, segsum, E);
    finalize<<<n2, 256, 0, stream>>>(index, pre, segsum, (float*)d_out, E);
}

// Round 3
// 648.236 us; speedup vs baseline: 1.3122x; 1.3122x over previous
//
#include <hip/hip_runtime.h>
#include <hip/hip_bf16.h>

typedef _Float16 f16x8 __attribute__((ext_vector_type(8)));
typedef float f32x4 __attribute__((ext_vector_type(4)));

#define NN 10000            // num_nodes (fixed by setup_inputs)
#define XROW 576            // 9*64 fp32 elements per edge row
#define BT_TOT 237568       // halves per tensor
// fragment-ordered bt layout (halves): phase bases / chunk strides
#define CB0 0
#define CB1 147456          // 24 chunks * 6144
#define CB2 409600          // CB1 + 32 * 8192
#define BUFH 8192           // halves per LDS buffer (16 KB)

// -------- weight packing: W fp32 [19][64][128] -> fp16 fragment-ordered bt, signs folded -----
// bt layout: per phase, per chunk nt (16 output cols = head h of out-block ob):
//   [q: kc=0..KC-1][lane=0..63][j=0..7] then [k: ...]  — unit (kc,lane) holds
//   BT[n = nt*16 + (lane&15)][k = kc*32 + (lane>>4)*8 + j]
__global__ void prep_bt(const float* __restrict__ Wq, const float* __restrict__ Wk,
                        _Float16* __restrict__ bt) {
    int g = blockIdx.x * 256 + threadIdx.x;
    if (g >= 2 * BT_TOT) return;
    int p, base, KC;
    if (g < CB1)      { p = 0; base = CB0; KC = 6; }
    else if (g < CB2) { p = 1; base = CB1; KC = 8; }
    else              { p = 2; base = CB2; KC = 4; }
    int local = g - base;
    int cs    = KC * 1024;               // halves per chunk (q+k)
    int chunk = local / cs;
    int r1    = local - chunk * cs;
    int t     = r1 / (KC * 512);         // 0 = q, 1 = k
    int r2    = r1 - t * (KC * 512);
    int kc    = r2 >> 9;
    int r3    = r2 & 511;
    int lane  = r3 >> 3, j = r3 & 7;
    int n = chunk * 16 + (lane & 15);
    int k = kc * 32 + ((lane >> 4) & 3) * 8 + j;
    int ib = k >> 6, c = k & 63;         // input 64-block, channel
    int ob = n >> 7, d = n & 127;        // output 128-block, channel
    int w, neg = 0;
    if (p == 0) {
        w = ib * 3 + ob;                 // Wm[i,o] i-major
    } else {
        int i, o, xn, yn, nb;
        if (p == 1) { i = ib & 1; xn = ib >> 1; o = ob & 1; yn = ob >> 1; nb = 9 + i * 4 + o * 2; }
        else        { xn = ib;   o = 0; yn = ob; nb = 17; }
        int which = xn ^ yn;             // 0 -> Wr, 1 -> Wi
        w = nb + which;
        neg = xn & (yn ^ 1);             // -Wi feeds the y_p path
    }
    const float* W = t ? Wk : Wq;
    float v = W[w * 8192 + c * 128 + d];
    if (neg) v = -v;
    bt[g] = (_Float16)v;
}

// -------- async global->LDS stage of one chunk (contiguous, fragment order) ------------------
__device__ __forceinline__ void stage_chunk(const ushort* __restrict__ src, ushort* dst,
                                            int units, int tid) {
    const int lane  = tid & 63;
    const int wbase = (tid >> 6) * 64;
    for (int u0 = wbase; u0 < units; u0 += 256) {
        const ushort* s = src + (size_t)(u0 + lane) * 8;
        ushort*       d = dst + (size_t)(u0 + lane) * 8;
        __builtin_amdgcn_global_load_lds(
            (const __attribute__((address_space(1))) unsigned int*)s,
            (__attribute__((address_space(3))) unsigned int*)d,
            16, 0, 0);
    }
}

// -------- main: per-wave 16-edge subtile, double-buffered async B staging --------------------
__launch_bounds__(256, 3)
__global__ void so2_attn_main(const float* __restrict__ xq, const float* __restrict__ xk,
                              const ushort* __restrict__ bt, const int* __restrict__ index,
                              float* __restrict__ pre, unsigned int* __restrict__ segmax, int E)
{
    __shared__ __align__(16) ushort lds[2 * BUFH];   // 32 KB double buffer

    const int tid  = threadIdx.x;
    const int lane = tid & 63;
    const int rsub = lane & 15, quad = lane >> 4;
    const int e0w  = blockIdx.x * 64 + (tid >> 6) * 16;

    float pacc[8][4];
#pragma unroll
    for (int h = 0; h < 8; ++h)
#pragma unroll
        for (int r = 0; r < 4; ++r) pacc[h][r] = 0.f;

    int eA = e0w + rsub; if (eA >= E) eA = E - 1;     // clamp A-row loads; writes guarded later
    const float* xqrow = xq + (size_t)eA * XROW;
    const float* xkrow = xk + (size_t)eA * XROW;

    constexpr int KC_[3]     = {6, 8, 4};            // MFMAs per chunk per tensor
    constexpr int NI_[3]     = {3, 4, 2};
    constexpr int NOB_[3]    = {3, 4, 2};
    constexpr int CBASE_[3]  = {CB0, CB1, CB2};
    constexpr int IORD[3][4] = {{0, 2, 6, 0}, {3, 7, 1, 5}, {8, 4, 0, 0}};

#pragma unroll
    for (int p = 0; p < 3; ++p) {
        const int KC = KC_[p], NI = NI_[p], NOB = NOB_[p];
        const int NC = NOB * 8;                       // chunks this phase
        const int cstride = KC * 1024;                // halves per chunk
        const int units   = KC * 128;                 // 16B units per chunk (2 tensors)
        const ushort* cbase = bt + CBASE_[p];

        // prologue: prefetch chunk 0 into buf0 (overlaps with A-fragment loads below)
        stage_chunk(cbase, lds, units, tid);

        // ---- A fragments: fp32 global loads, converted to fp16 in-register ----
        f16x8 aq[8], ak[8];
#pragma unroll
        for (int i = 0; i < NI; ++i)
#pragma unroll
            for (int kh = 0; kh < 2; ++kh) {
                int off = IORD[p][i] * 64 + kh * 32 + quad * 8;
                f32x4 q0 = *(const f32x4*)(xqrow + off);
                f32x4 q1 = *(const f32x4*)(xqrow + off + 4);
                f32x4 k0 = *(const f32x4*)(xkrow + off);
                f32x4 k1 = *(const f32x4*)(xkrow + off + 4);
                f16x8 fq, fk;
#pragma unroll
                for (int j = 0; j < 4; ++j) {
                    fq[j] = (_Float16)q0[j]; fq[4 + j] = (_Float16)q1[j];
                    fk[j] = (_Float16)k0[j]; fk[4 + j] = (_Float16)k1[j];
                }
                aq[i * 2 + kh] = fq;
                ak[i * 2 + kh] = fk;
            }

        for (int ob = 0; ob < NOB; ++ob) {
#pragma unroll
            for (int h = 0; h < 8; ++h) {
                const int c = ob * 8 + h;
                __syncthreads();                      // chunk c's DMA complete (all waves)
                if (c + 1 < NC)
                    stage_chunk(cbase + (size_t)(c + 1) * cstride,
                                lds + ((c + 1) & 1) * BUFH, units, tid);
                const ushort* bq = lds + (c & 1) * BUFH;
                const ushort* bk = bq + KC * 512;
                f32x4 qa = {0.f, 0.f, 0.f, 0.f}, ka = {0.f, 0.f, 0.f, 0.f};
#pragma unroll
                for (int kc = 0; kc < KC; ++kc) {
                    f16x8 fbq = *(const f16x8*)(bq + (size_t)(kc * 64 + lane) * 8);
                    f16x8 fbk = *(const f16x8*)(bk + (size_t)(kc * 64 + lane) * 8);
                    qa = __builtin_amdgcn_mfma_f32_16x16x32_f16(aq[kc], fbq, qa, 0, 0, 0);
                    ka = __builtin_amdgcn_mfma_f32_16x16x32_f16(ak[kc], fbk, ka, 0, 0, 0);
                }
#pragma unroll
                for (int r = 0; r < 4; ++r) pacc[h][r] += qa[r] * ka[r];
            }
        }
        __syncthreads();                              // last chunk's readers done before next phase reuses buffers
    }

    // ---- epilogue: reduce 16 channels per head across lanes, write pre + seg-max atomic ----
#pragma unroll
    for (int h = 0; h < 8; ++h) {
        float v[4];
#pragma unroll
        for (int r = 0; r < 4; ++r) v[r] = pacc[h][r] * 0.25f;   // * K_C^-0.5
#pragma unroll
        for (int off = 8; off >= 1; off >>= 1)
#pragma unroll
            for (int r = 0; r < 4; ++r) v[r] += __shfl_xor(v[r], off, 64);
        if (rsub == h) {
#pragma unroll
            for (int r = 0; r < 4; ++r) {
                int e = e0w + quad * 4 + r;
                if (e < E) {
                    pre[(size_t)e * 8 + h] = v[r];
                    unsigned u = __float_as_uint(v[r]);
                    u = (u & 0x80000000u) ? ~u : (u | 0x80000000u);   // order-preserving map
                    atomicMax(&segmax[(size_t)index[e] * 8 + h], u);
                }
            }
        }
    }
}

// ---------------- softmax passes ----------------
__global__ void exp_seg(const int* __restrict__ index, float* __restrict__ pre,
                        const unsigned* __restrict__ segmax, float* __restrict__ segsum, int E) {
    int idx = blockIdx.x * 256 + threadIdx.x;
    if (idx >= E * 8) return;
    int e = idx >> 3, h = idx & 7;
    unsigned um = segmax[(size_t)index[e] * 8 + h];
    unsigned ub = (um & 0x80000000u) ? (um & 0x7FFFFFFFu) : ~um;
    float m = __uint_as_float(ub);
    float ex = __expf(pre[idx] - m);
    pre[idx] = ex;
    atomicAdd(&segsum[(size_t)index[e] * 8 + h], ex);
}

__global__ void finalize(const int* __restrict__ index, const float* __restrict__ pre,
                         const float* __restrict__ segsum, float* __restrict__ out, int E) {
    int idx = blockIdx.x * 256 + threadIdx.x;
    if (idx >= E * 8) return;
    int e = idx >> 3, h = idx & 7;
    float s = segsum[(size_t)index[e] * 8 + h] + 1e-16f;
    out[idx] = pre[idx] / s;
}

extern "C" void kernel_launch(void* const* d_in, const int* in_sizes, int n_in,
                              void* d_out, int out_size, void* d_ws, size_t ws_size,
                              hipStream_t stream) {
    const float* xq = (const float*)d_in[0];
    const float* xk = (const float*)d_in[1];
    const float* Wq = (const float*)d_in[2];
    const float* Wk = (const float*)d_in[3];
    const int* index = (const int*)d_in[4];
    const int E = in_sizes[0] / XROW;        // 100000

    char* ws = (char*)d_ws;
    _Float16* bt     = (_Float16*)ws;                                 // 2*BT_TOT fp16 = 950272 B
    float*    pre    = (float*)(ws + (size_t)2 * BT_TOT * 2);         // E*8 f32
    unsigned* segmax = (unsigned*)((char*)pre + (size_t)E * 8 * 4);   // NN*8 u32
    float*    segsum = (float*)((char*)segmax + (size_t)NN * 8 * 4);  // NN*8 f32

    hipMemsetAsync(segmax, 0, (size_t)NN * 8 * 4 * 2, stream);        // segmax enc-bottom + segsum 0

    prep_bt<<<(2 * BT_TOT + 255) / 256, 256, 0, stream>>>(Wq, Wk, bt);
    so2_attn_main<<<(E + 63) / 64, 256, 0, stream>>>(xq, xk, (const ushort*)bt, index,
                                                     pre, segmax, E);
    int n2 = (E * 8 + 255) / 256;
    exp_seg<<<n2, 256, 0, stream>>>(index, pre, segmax, segsum, E);
    finalize<<<n2, 256, 0, stream>>>(index, pre, segsum, (float*)d_out, E);
}